// Round 11
// baseline (1282.882 us; speedup 1.0000x reference)
//
#include <hip/hip_runtime.h>
#include <hip/hip_bf16.h>

#define IN_DIM 1024
#define H_DIM  1024
#define C_DIM  16
#define B_DIM  4096
#define K_DIM  2048      // IN + H
#define N_DIM  32768     // C * 2H
#define M_DIM  4096      // B
#define NT     64        // K_DIM / 32 K-steps

typedef __attribute__((ext_vector_type(8))) short short8;
typedef __attribute__((ext_vector_type(4))) float f32x4;

__device__ __forceinline__ unsigned short f2bf_rne(float f) {
  union { float f; unsigned u; } a; a.f = f;
  unsigned r = a.u + 0x7FFFu + ((a.u >> 16) & 1u);
  return (unsigned short)(r >> 16);
}

// Pack rows: out[r][0:1024] = bf16(xs[r][:]), out[r][1024:2048] = bf16(hs[r][:])
__global__ void convert_pack_kernel(const float* __restrict__ xs,
                                    const float* __restrict__ hs,
                                    unsigned short* __restrict__ out,
                                    int rows) {
  long total = (long)rows * (K_DIM / 8);
  for (long i = blockIdx.x * (long)blockDim.x + threadIdx.x; i < total;
       i += (long)gridDim.x * blockDim.x) {
    long e = i * 8;
    int r = (int)(e >> 11);
    int k = (int)(e & 2047);
    const float* src = (k < IN_DIM) ? (xs + (long)r * IN_DIM + k)
                                    : (hs + (long)r * H_DIM + (k - IN_DIM));
    float4 v0 = *(const float4*)(src);
    float4 v1 = *(const float4*)(src + 4);
    union { unsigned short u[8]; short8 s; } p;
    p.u[0] = f2bf_rne(v0.x); p.u[1] = f2bf_rne(v0.y);
    p.u[2] = f2bf_rne(v0.z); p.u[3] = f2bf_rne(v0.w);
    p.u[4] = f2bf_rne(v1.x); p.u[5] = f2bf_rne(v1.y);
    p.u[6] = f2bf_rne(v1.z); p.u[7] = f2bf_rne(v1.w);
    *(short8*)(out + e) = p.s;
  }
}

__device__ __forceinline__ void gl16(const short* g, short* l) {
  __builtin_amdgcn_global_load_lds(
      (const __attribute__((address_space(1))) unsigned int*)g,
      (__attribute__((address_space(3))) unsigned int*)l, 16, 0, 0);
}

// C = A(M x K) * Bt(N x K)^T + bias, fused sigmoid/tanh epilogue.
// OCCUPANCY PIVOT (m97 mechanism): 128x128 tile, BK=32, 4 waves (2x2),
// wave tile 64x64. A-fragments load DIRECTLY from global (no LDS) — A is
// L2/L3-resident; B double-buffered in 16 KiB LDS via builtin DMA.
// One __syncthreads per K-step; all waits compiler-managed. ~3 blocks/CU
// co-resident provide the MFMA/mem overlap that intra-block scheduling
// failed to deliver in rounds 2-10 (cross-block TLP, m114).
// Issue order per step: A-loads -> stage(next B) -> B ds_reads -> MFMA ->
// __syncthreads. (A first so its fine-grained vmcnt waits exclude stages.)
__global__ void __launch_bounds__(256, 3)
gemm_act_kernel(const short* __restrict__ A,   // [M][K] bf16 bits
                const short* __restrict__ Bt,  // [N][K] bf16 bits
                const float* __restrict__ bias,// [N]
                float* __restrict__ out) {
  __shared__ short lds[8192];   // B dbuf: [2][128 rows][32 cols] bf16

  // bijective XCD swizzle (nwg = 8192, divisible by 8); m-fastest tiling
  int cpx = (int)gridDim.x >> 3;
  int wg  = ((int)blockIdx.x & 7) * cpx + ((int)blockIdx.x >> 3);
  int mt = wg & 31;            // M/128 = 32 tiles (fast: share B panel in L2)
  int nt = wg >> 5;            // N/128 = 256 tiles
  int m0 = mt * 128;
  int n0 = nt * 128;

  const int tid  = (int)threadIdx.x;
  const int lane = tid & 63;
  const int wid  = tid >> 6;
  const int wrow = (wid >> 1) * 64;   // wave row offset in tile
  const int wcol = (wid & 1) * 64;    // wave col offset in tile

  const int fr = lane & 15;
  const int g8 = lane >> 4;           // 16B k-chunk 0..3 within BK=32

  // ---- epilogue constants (bias hoisted before loop) ----
  const int crow = (lane >> 4) * 4;
  const int ccol = lane & 15;
  const long HALF = (long)B_DIM * C_DIM * H_DIM;  // 67108864
  float bia[4]; int cg[4], og[4];
#pragma unroll
  for (int ni = 0; ni < 4; ++ni) {
    int gn = n0 + wcol + ni * 16 + ccol;
    bia[ni] = bias[gn];
    cg[ni] = gn >> 11;
    og[ni] = gn & 2047;
  }

  // ---- B staging (swizzled global source, lane-linear LDS dest) ----
  const int srow = tid >> 2;                 // 0..63
  const int sc   = (tid & 3) ^ (srow & 3);   // swizzled 16B chunk (4/row)
  const short* Bsrc = Bt + (long)(n0 + srow) * K_DIM + sc * 8;
  // LDS[r][c] = global[r][c ^ (r&3)]; read uses same XOR (involution).

  // ---- A direct-load base: row = m0+wrow+mi*16+fr, k = t*32 + g8*8 ----
  const short* Abase = A + (long)(m0 + wrow + fr) * K_DIM + g8 * 8;

  // ---- B fragment LDS offsets (shorts) ----
  int boff[4];
#pragma unroll
  for (int ni = 0; ni < 4; ++ni) {
    int r = wcol + ni * 16 + fr;
    boff[ni] = r * 32 + ((g8 ^ (r & 3)) << 3);
  }

  f32x4 acc[4][4] = {};

  auto stage = [&](int t, int parity) {   // B tile t -> buf[parity]
    const short* g = Bsrc + t * 32;
    short* d = lds + parity * 4096 + tid * 8;
    gl16(g,                    d);
    gl16(g + 64 * K_DIM,       d + 2048);
  };

  auto body = [&](int t, int parity) {
    // A fragments (global, L2-hot): 4 x b128
    short8 av[4];
#pragma unroll
    for (int mi = 0; mi < 4; ++mi)
      av[mi] = *(const short8*)(Abase + (long)mi * 16 * K_DIM + t * 32);
    // prefetch next B tile into other buffer
    if (t + 1 < NT) stage(t + 1, parity ^ 1);
    // B fragments (LDS)
    short8 bv[4];
#pragma unroll
    for (int ni = 0; ni < 4; ++ni)
      bv[ni] = *(const short8*)(lds + parity * 4096 + boff[ni]);
    // 16 MFMA
#pragma unroll
    for (int mi = 0; mi < 4; ++mi)
#pragma unroll
      for (int ni = 0; ni < 4; ++ni)
        acc[mi][ni] = __builtin_amdgcn_mfma_f32_16x16x32_bf16(av[mi], bv[ni], acc[mi][ni], 0, 0, 0);
    __syncthreads();   // drains stage DMA + frag reads; gates buffer reuse
  };

  stage(0, 0);
  __syncthreads();
  for (int t = 0; t < NT; t += 2) {
    body(t,     0);
    body(t + 1, 1);
  }

  // ---- epilogue: C/D layout col=lane&15, row=(lane>>4)*4+j ----
#pragma unroll
  for (int mi = 0; mi < 4; ++mi) {
    int gb0 = m0 + wrow + mi * 16 + crow;
#pragma unroll
    for (int ni = 0; ni < 4; ++ni) {
      int c = cg[ni], o = og[ni];
#pragma unroll
      for (int j = 0; j < 4; ++j) {
        float v = acc[mi][ni][j] + bia[ni];
        long b = gb0 + j;
        if (o < H_DIM) {  // input_gate = sigmoid -> output 1 (second half)
          float r = 1.0f / (1.0f + __expf(-v));
          __builtin_nontemporal_store(r, &out[HALF + (b * C_DIM + c) * H_DIM + o]);
        } else {          // cell_input = tanh -> output 0 (first half)
          float av2 = fabsf(v);
          float e = __expf(-2.0f * av2);
          float r = (1.0f - e) / (1.0f + e);
          r = (v < 0.0f) ? -r : r;
          __builtin_nontemporal_store(r, &out[(b * C_DIM + c) * H_DIM + (o - H_DIM)]);
        }
      }
    }
  }
}

// Correctness-only fallback if workspace is too small for bf16 staging.
__global__ void fallback_kernel(const float* __restrict__ x,
                                const float* __restrict__ h,
                                const float* __restrict__ Wx,
                                const float* __restrict__ bx,
                                const float* __restrict__ Wh,
                                float* __restrict__ out) {
  int b = blockIdx.x;
  int c = blockIdx.y;
  __shared__ float lx[IN_DIM], lh[H_DIM];
  for (int i = threadIdx.x; i < IN_DIM; i += blockDim.x) {
    lx[i] = x[(long)b * IN_DIM + i];
    lh[i] = h[(long)b * H_DIM + i];
  }
  __syncthreads();
  const long HALF = (long)B_DIM * C_DIM * H_DIM;
  for (int o = threadIdx.x; o < 2 * H_DIM; o += blockDim.x) {
    const float* wx = Wx + ((long)c * 2 * H_DIM + o) * IN_DIM;
    const float* wh = Wh + ((long)c * 2 * H_DIM + o) * H_DIM;
    float acc = bx[c * 2 * H_DIM + o];
    for (int k = 0; k < IN_DIM; ++k) acc += lx[k] * wx[k];
    for (int k = 0; k < H_DIM; ++k) acc += lh[k] * wh[k];
    if (o < H_DIM) {
      out[HALF + ((long)b * C_DIM + c) * H_DIM + o] = 1.0f / (1.0f + __expf(-acc));
    } else {
      float av = fabsf(acc);
      float t = __expf(-2.0f * av);
      float r = (1.0f - t) / (1.0f + t);
      out[((long)b * C_DIM + c) * H_DIM + (o - H_DIM)] = (acc < 0.0f) ? -r : r;
    }
  }
}

extern "C" void kernel_launch(void* const* d_in, const int* in_sizes, int n_in,
                              void* d_out, int out_size, void* d_ws, size_t ws_size,
                              hipStream_t stream) {
  const float* x  = (const float*)d_in[0];   // (B, IN)
  const float* h  = (const float*)d_in[1];   // (B, H)
  const float* Wx = (const float*)d_in[2];   // (C, 2H, IN)
  const float* bx = (const float*)d_in[3];   // (C, 2H)
  const float* Wh = (const float*)d_in[4];   // (C, 2H, H)
  float* out = (float*)d_out;                // [cell_input | input_gate], each (B,C,H)

  const size_t needA = (size_t)M_DIM * K_DIM * sizeof(short);  // 16 MiB
  const size_t needB = (size_t)N_DIM * K_DIM * sizeof(short);  // 128 MiB
  if (ws_size < needA + needB) {
    dim3 g(B_DIM, C_DIM);
    fallback_kernel<<<g, 256, 0, stream>>>(x, h, Wx, bx, Wh, out);
    return;
  }

  unsigned short* Abf = (unsigned short*)d_ws;
  unsigned short* Bbf = (unsigned short*)((char*)d_ws + needA);

  convert_pack_kernel<<<2048, 256, 0, stream>>>(x, h, Abf, M_DIM);
  convert_pack_kernel<<<4096, 256, 0, stream>>>(Wx, Wh, Bbf, N_DIM);

  gemm_act_kernel<<<8192, 256, 0, stream>>>((const short*)Abf, (const short*)Bbf,
                                            bx, out);
}

// Round 12
// 822.080 us; speedup vs baseline: 1.5605x; 1.5605x over previous
//
#include <hip/hip_runtime.h>
#include <hip/hip_bf16.h>

#define IN_DIM 1024
#define H_DIM  1024
#define C_DIM  16
#define B_DIM  4096
#define K_DIM  2048      // IN + H
#define N_DIM  32768     // C * 2H
#define M_DIM  4096      // B
#define NT     32        // K_DIM / 64 K-steps

typedef __attribute__((ext_vector_type(8))) short short8;
typedef __attribute__((ext_vector_type(4))) float f32x4;

__device__ __forceinline__ unsigned short f2bf_rne(float f) {
  union { float f; unsigned u; } a; a.f = f;
  unsigned r = a.u + 0x7FFFu + ((a.u >> 16) & 1u);
  return (unsigned short)(r >> 16);
}

// Pack rows: out[r][0:1024] = bf16(xs[r][:]), out[r][1024:2048] = bf16(hs[r][:])
__global__ void convert_pack_kernel(const float* __restrict__ xs,
                                    const float* __restrict__ hs,
                                    unsigned short* __restrict__ out,
                                    int rows) {
  long total = (long)rows * (K_DIM / 8);
  for (long i = blockIdx.x * (long)blockDim.x + threadIdx.x; i < total;
       i += (long)gridDim.x * blockDim.x) {
    long e = i * 8;
    int r = (int)(e >> 11);
    int k = (int)(e & 2047);
    const float* src = (k < IN_DIM) ? (xs + (long)r * IN_DIM + k)
                                    : (hs + (long)r * H_DIM + (k - IN_DIM));
    float4 v0 = *(const float4*)(src);
    float4 v1 = *(const float4*)(src + 4);
    union { unsigned short u[8]; short8 s; } p;
    p.u[0] = f2bf_rne(v0.x); p.u[1] = f2bf_rne(v0.y);
    p.u[2] = f2bf_rne(v0.z); p.u[3] = f2bf_rne(v0.w);
    p.u[4] = f2bf_rne(v1.x); p.u[5] = f2bf_rne(v1.y);
    p.u[6] = f2bf_rne(v1.z); p.u[7] = f2bf_rne(v1.w);
    *(short8*)(out + e) = p.s;
  }
}

__device__ __forceinline__ void gl16(const short* g, short* l) {
  __builtin_amdgcn_global_load_lds(
      (const __attribute__((address_space(1))) unsigned int*)g,
      (__attribute__((address_space(3))) unsigned int*)l, 16, 0, 0);
}

// C = A(M x K) * Bt(N x K)^T + bias, fused sigmoid/tanh epilogue.
// ROUND-12 SIMPLIFICATION: same geometry as rounds 9-10 (256x256 tile,
// BK=64, 8 waves 2Mx4N, wave tile 128x64, 128 KiB double buffer), but the
// K-loop has ONE barrier per K-step and ZERO hand-inserted waits/phases:
//   { stage-all(t+1 -> other buf); 24 ds_reads + 64 MFMA straight-line;
//     __syncthreads(); }
// Rationale (rounds 2-10 ledger): 4-8 barriers/step + hand vmcnt serialized
// the LDS port against the MFMA pipe (best variant was the one with fewest
// barriers). m97's proven 874 TF uses exactly this 1-barrier shape; the
// compiler emits fine-grained lgkmcnt inside the compute region (r109) and
// the end-of-step __syncthreads (vmcnt0+lgkm0 drain) is the only sync.
// Race-freedom: 2 buffers; step t writes buf^1, reads buf; all reads/DMA of
// a step complete at its barrier -> no same-buffer overlap is possible.
__global__ void __launch_bounds__(512, 2)
gemm_act_kernel(const short* __restrict__ A,   // [M][K] bf16 bits
                const short* __restrict__ Bt,  // [N][K] bf16 bits
                const float* __restrict__ bias,// [N]
                float* __restrict__ out) {
  extern __shared__ short lds[];
  // shorts: A0=0, A1=16384, B0=32768, B1=49152

  // bijective XCD swizzle (nwg = 2048, divisible by 8); m-fastest tiling
  int cpx = (int)gridDim.x >> 3;
  int wg  = ((int)blockIdx.x & 7) * cpx + ((int)blockIdx.x >> 3);
  int mt = wg & 15;           // M/256 = 16 tiles
  int nt = wg >> 4;           // N/256 = 128 tiles
  int m0 = mt * 256;
  int n0 = nt * 256;

  const int tid  = (int)threadIdx.x;
  const int lane = tid & 63;
  const int wid  = tid >> 6;
  const int wr   = wid >> 2;   // wave rows wr*128
  const int wc   = wid & 3;    // wave cols wc*64

  // ---- epilogue constants (hoisted before any DMA) ----
  const int crow = (lane >> 4) * 4;
  const int ccol = lane & 15;
  const long HALF = (long)B_DIM * C_DIM * H_DIM;  // 67108864
  float bia[4]; int cg[4], og[4];
#pragma unroll
  for (int ni = 0; ni < 4; ++ni) {
    int gn = n0 + wc * 64 + ni * 16 + ccol;
    bia[ni] = bias[gn];
    cg[ni] = gn >> 11;
    og[ni] = gn & 2047;
  }

  // ---- staging (T2: swizzled global source, lane-linear LDS dest) ----
  const int srow = tid >> 3;                 // 0..63 row within quarter
  const int sc   = (tid & 7) ^ (srow & 7);   // swizzled src 16B chunk
  const short* Abase = A  + (long)(m0 + srow) * K_DIM + sc * 8;
  const short* Bbase = Bt + (long)(n0 + srow) * K_DIM + sc * 8;
  const int dstT = tid * 8;                  // per-thread dest (shorts)

  // stage one full 256x64 A-tile + B-tile of K-step kt into buffer b
  auto stageAll = [&](int kt, int b) {
    const short* Ag = Abase + kt * 64;
    const short* Bg = Bbase + kt * 64;
    short* Ad = lds + b * 16384 + dstT;
    short* Bd = lds + 32768 + b * 16384 + dstT;
    gl16(Ag,                      Ad);
    gl16(Ag + (long) 64 * K_DIM,  Ad + 4096);
    gl16(Ag + (long)128 * K_DIM,  Ad + 8192);
    gl16(Ag + (long)192 * K_DIM,  Ad + 12288);
    gl16(Bg,                      Bd);
    gl16(Bg + (long) 64 * K_DIM,  Bd + 4096);
    gl16(Bg + (long)128 * K_DIM,  Bd + 8192);
    gl16(Bg + (long)192 * K_DIM,  Bd + 12288);
  };

  // ---- fragment LDS base offsets (shorts); mi adds mi*1024 (immediate) ----
  const int fr = lane & 15;
  const int g8 = lane >> 4;
  int aoff[2], boff[2];
#pragma unroll
  for (int kk = 0; kk < 2; ++kk) {
    aoff[kk] = (wr * 128 + fr) * 64 + (((kk * 4 + g8) ^ (fr & 7)) << 3);
    boff[kk] = (wc * 64  + fr) * 64 + (((kk * 4 + g8) ^ (fr & 7)) << 3);
  }

  f32x4 acc[8][4] = {};

  // ---- prologue ----
  stageAll(0, 0);
  __syncthreads();   // drains prologue DMA (vmcnt0) for all waves

  for (int t = 0; t < NT; ++t) {
    const int b = t & 1;
    if (t + 1 < NT) stageAll(t + 1, b ^ 1);   // issue early; lands under compute
    const int bufA = b * 16384;
    const int bufB = 32768 + b * 16384;
    short8 av[8], bv[4];
    // kk = 0
#pragma unroll
    for (int mi = 0; mi < 8; ++mi)
      av[mi] = *(const short8*)(lds + bufA + aoff[0] + mi * 1024);
#pragma unroll
    for (int ni = 0; ni < 4; ++ni)
      bv[ni] = *(const short8*)(lds + bufB + boff[0] + ni * 1024);
#pragma unroll
    for (int mi = 0; mi < 8; ++mi)
#pragma unroll
      for (int ni = 0; ni < 4; ++ni)
        acc[mi][ni] = __builtin_amdgcn_mfma_f32_16x16x32_bf16(av[mi], bv[ni], acc[mi][ni], 0, 0, 0);
    // kk = 1
#pragma unroll
    for (int mi = 0; mi < 8; ++mi)
      av[mi] = *(const short8*)(lds + bufA + aoff[1] + mi * 1024);
#pragma unroll
    for (int ni = 0; ni < 4; ++ni)
      bv[ni] = *(const short8*)(lds + bufB + boff[1] + ni * 1024);
#pragma unroll
    for (int mi = 0; mi < 8; ++mi)
#pragma unroll
      for (int ni = 0; ni < 4; ++ni)
        acc[mi][ni] = __builtin_amdgcn_mfma_f32_16x16x32_bf16(av[mi], bv[ni], acc[mi][ni], 0, 0, 0);
    __syncthreads();   // single sync: drains this step's DMA + all reads
  }

  // ---- epilogue: C/D layout col=lane&15, row=(lane>>4)*4+j ----
#pragma unroll
  for (int mi = 0; mi < 8; ++mi) {
    int gb0 = m0 + wr * 128 + mi * 16 + crow;
#pragma unroll
    for (int ni = 0; ni < 4; ++ni) {
      int c = cg[ni], o = og[ni];
#pragma unroll
      for (int j = 0; j < 4; ++j) {
        float v = acc[mi][ni][j] + bia[ni];
        long bb = gb0 + j;
        if (o < H_DIM) {  // input_gate = sigmoid -> output 1 (second half)
          float r = 1.0f / (1.0f + __expf(-v));
          __builtin_nontemporal_store(r, &out[HALF + (bb * C_DIM + c) * H_DIM + o]);
        } else {          // cell_input = tanh -> output 0 (first half)
          float av2 = fabsf(v);
          float e = __expf(-2.0f * av2);
          float r = (1.0f - e) / (1.0f + e);
          r = (v < 0.0f) ? -r : r;
          __builtin_nontemporal_store(r, &out[(bb * C_DIM + c) * H_DIM + (o - H_DIM)]);
        }
      }
    }
  }
}

// Correctness-only fallback if workspace is too small for bf16 staging.
__global__ void fallback_kernel(const float* __restrict__ x,
                                const float* __restrict__ h,
                                const float* __restrict__ Wx,
                                const float* __restrict__ bx,
                                const float* __restrict__ Wh,
                                float* __restrict__ out) {
  int b = blockIdx.x;
  int c = blockIdx.y;
  __shared__ float lx[IN_DIM], lh[H_DIM];
  for (int i = threadIdx.x; i < IN_DIM; i += blockDim.x) {
    lx[i] = x[(long)b * IN_DIM + i];
    lh[i] = h[(long)b * H_DIM + i];
  }
  __syncthreads();
  const long HALF = (long)B_DIM * C_DIM * H_DIM;
  for (int o = threadIdx.x; o < 2 * H_DIM; o += blockDim.x) {
    const float* wx = Wx + ((long)c * 2 * H_DIM + o) * IN_DIM;
    const float* wh = Wh + ((long)c * 2 * H_DIM + o) * H_DIM;
    float acc = bx[c * 2 * H_DIM + o];
    for (int k = 0; k < IN_DIM; ++k) acc += lx[k] * wx[k];
    for (int k = 0; k < H_DIM; ++k) acc += lh[k] * wh[k];
    if (o < H_DIM) {
      out[HALF + ((long)b * C_DIM + c) * H_DIM + o] = 1.0f / (1.0f + __expf(-acc));
    } else {
      float av = fabsf(acc);
      float t = __expf(-2.0f * av);
      float r = (1.0f - t) / (1.0f + t);
      out[((long)b * C_DIM + c) * H_DIM + (o - H_DIM)] = (acc < 0.0f) ? -r : r;
    }
  }
}

extern "C" void kernel_launch(void* const* d_in, const int* in_sizes, int n_in,
                              void* d_out, int out_size, void* d_ws, size_t ws_size,
                              hipStream_t stream) {
  const float* x  = (const float*)d_in[0];   // (B, IN)
  const float* h  = (const float*)d_in[1];   // (B, H)
  const float* Wx = (const float*)d_in[2];   // (C, 2H, IN)
  const float* bx = (const float*)d_in[3];   // (C, 2H)
  const float* Wh = (const float*)d_in[4];   // (C, 2H, H)
  float* out = (float*)d_out;                // [cell_input | input_gate], each (B,C,H)

  const size_t needA = (size_t)M_DIM * K_DIM * sizeof(short);  // 16 MiB
  const size_t needB = (size_t)N_DIM * K_DIM * sizeof(short);  // 128 MiB
  if (ws_size < needA + needB) {
    dim3 g(B_DIM, C_DIM);
    fallback_kernel<<<g, 256, 0, stream>>>(x, h, Wx, bx, Wh, out);
    return;
  }

  unsigned short* Abf = (unsigned short*)d_ws;
  unsigned short* Bbf = (unsigned short*)((char*)d_ws + needA);

  convert_pack_kernel<<<2048, 256, 0, stream>>>(x, h, Abf, M_DIM);
  convert_pack_kernel<<<4096, 256, 0, stream>>>(Wx, Wh, Bbf, N_DIM);

  (void)hipFuncSetAttribute((const void*)gemm_act_kernel,
                            hipFuncAttributeMaxDynamicSharedMemorySize, 131072);
  gemm_act_kernel<<<2048, 512, 131072, stream>>>((const short*)Abf, (const short*)Bbf,
                                                 bx, out);
}